// Round 1
// baseline (1349.965 us; speedup 1.0000x reference)
//
#include <hip/hip_runtime.h>

// GroupRenderer: segment-sum of w[s]*group[s,:] over sorted ray_indices,
// then F.normalize(p=2, dim=-1) over groups of S=8.
// group: [ns, 16, 8] f32; weights: [ns,1] f32; ray_indices: [ns] i32 sorted;
// out: [num_rays, 16, 8] f32.  LS = 128 floats per sample/ray row.

#define LS 128
#define EPS 1e-12f

// starts[r] = lower_bound(ray_indices, r), r in [0, num_rays]; starts in d_ws.
__global__ void find_starts(const int* __restrict__ ray_indices, int ns,
                            int num_rays, int* __restrict__ starts) {
    int r = blockIdx.x * blockDim.x + threadIdx.x;
    if (r > num_rays) return;
    int lo = 0, hi = ns;
    while (lo < hi) {
        int mid = (lo + hi) >> 1;          // ns < 2^31, no overflow
        if (ray_indices[mid] < r) lo = mid + 1;
        else hi = mid;
    }
    starts[r] = lo;
}

// One ray per 64-lane wave. Lane split: h = lane>>5 picks sample parity
// (even/odd sample of a pair), g = lane&31 picks the float4 slot in the
// 128-float row. Each unrolled iteration streams 8 sample rows (4 KiB)
// with all 8 row-loads + 8 weight-loads independent -> 4x the in-flight
// bytes of the previous 2-rays/wave unroll-2 version, and no intra-wave
// trip-count divergence (both halves share the same loop bounds).
// Pointer + constant-offset addressing lets the compiler fold the 4 row
// loads into global_load_dwordx4 with offset: immediates off one base.
__global__ __launch_bounds__(256) void accumulate_normalize(
        const float4* __restrict__ group4,   // [ns, 32] float4
        const float*  __restrict__ weights,  // [ns]
        const int*    __restrict__ starts,   // [num_rays+1]
        float4*       __restrict__ out4,     // [num_rays, 32] float4
        int num_rays) {
    const int lane = threadIdx.x & 63;
    const int h    = lane >> 5;                     // sample-pair half
    const int g    = lane & 31;                     // float4 slot in row
    const int ray  = blockIdx.x * 4 + (threadIdx.x >> 6);
    if (ray >= num_rays) return;

    const int s0 = starts[ray];
    const int s1 = starts[ray + 1];

    float4 acc = make_float4(0.f, 0.f, 0.f, 0.f);
    const float4* p  = group4  + (size_t)(s0 + h) * 32 + g;
    const float*  wp = weights + s0 + h;

    int s = s0;
    // 8 samples per iteration: halves h=0/1 each take 4 (constant offsets).
    for (; s + 8 <= s1; s += 8, p += 256, wp += 8) {
        const float  w0 = wp[0], w1 = wp[2], w2 = wp[4], w3 = wp[6];
        const float4 v0 = p[0];
        const float4 v1 = p[64];
        const float4 v2 = p[128];
        const float4 v3 = p[192];
        acc.x += w0 * v0.x; acc.y += w0 * v0.y;
        acc.z += w0 * v0.z; acc.w += w0 * v0.w;
        acc.x += w1 * v1.x; acc.y += w1 * v1.y;
        acc.z += w1 * v1.z; acc.w += w1 * v1.w;
        acc.x += w2 * v2.x; acc.y += w2 * v2.y;
        acc.z += w2 * v2.z; acc.w += w2 * v2.w;
        acc.x += w3 * v3.x; acc.y += w3 * v3.y;
        acc.z += w3 * v3.z; acc.w += w3 * v3.w;
    }
    // Tail: up to 7 samples, 2 per iteration with per-half predication.
    for (; s < s1; s += 2, p += 64, wp += 2) {
        if (s + h < s1) {
            const float  w = wp[0];
            const float4 v = p[0];
            acc.x += w * v.x; acc.y += w * v.y;
            acc.z += w * v.z; acc.w += w * v.w;
        }
    }

    // Combine even/odd sample halves (lane ^ 32): full ray sum in all lanes.
    acc.x += __shfl_xor(acc.x, 32, 64);
    acc.y += __shfl_xor(acc.y, 32, 64);
    acc.z += __shfl_xor(acc.z, 32, 64);
    acc.w += __shfl_xor(acc.w, 32, 64);

    // Sum of squares over the 8-float S-group: self-dot + partner (g ^ 1).
    float ss = acc.x * acc.x + acc.y * acc.y + acc.z * acc.z + acc.w * acc.w;
    ss += __shfl_xor(ss, 1, 64);
    const float inv = 1.0f / fmaxf(sqrtf(ss), EPS);
    acc.x *= inv; acc.y *= inv; acc.z *= inv; acc.w *= inv;

    if (h == 0) out4[(size_t)ray * 32 + g] = acc;   // 512 B per ray, coalesced
}

extern "C" void kernel_launch(void* const* d_in, const int* in_sizes, int n_in,
                              void* d_out, int out_size, void* d_ws, size_t ws_size,
                              hipStream_t stream) {
    const float* group       = (const float*)d_in[0];
    const float* weights     = (const float*)d_in[1];
    const int*   ray_indices = (const int*)d_in[2];   // jax canonicalizes to i32

    const int ns       = in_sizes[0] / LS;
    const int num_rays = out_size / LS;               // 65536

    int* starts = (int*)d_ws;                         // (num_rays+1) ints

    {
        int n = num_rays + 1;
        find_starts<<<(n + 255) / 256, 256, 0, stream>>>(ray_indices, ns,
                                                         num_rays, starts);
    }
    {
        int blocks = (num_rays + 3) / 4;              // 1 ray per wave, 4/block
        accumulate_normalize<<<blocks, 256, 0, stream>>>(
            (const float4*)group, weights, starts, (float4*)d_out, num_rays);
    }
}